// Round 5
// baseline (221.179 us; speedup 1.0000x reference)
//
#include <hip/hip_runtime.h>
#include <hip/hip_bf16.h>

typedef __hip_bfloat16 bf16;
typedef __attribute__((ext_vector_type(8))) short short8;
typedef __attribute__((ext_vector_type(4))) float float4v;

#define NN   768
#define NEPS 767

// ---- converted fp32 constants ----
#define C_NUC   0
#define C_F     2304
#define C_MP1W0 2656
#define C_MP1B0 5728
#define C_MP1W1 5760
#define C_MP1B1 6784
#define C_UP1W0 6816
#define C_UP1B0 10912
#define C_UP1W1 10976
#define C_UP1B1 15072
#define C_MP2W0 15136
#define C_MP2B0 20256
#define C_MP2W1 20288
#define C_MP2B1 21312
#define C_UP2W0 21344
#define C_UP2B0 27488
#define C_UP2W1 27552
#define C_UP2B1 31648
#define C_NOW0  31712
#define C_NOB0  32192
#define C_NOW1  32195
#define C_NOEMB 32204
#define C_GOW0  32234
#define C_GOB0  32394
#define C_GOW1  32395
#define C_GOB1  32396
__device__ __align__(16) float g_c[32400];

// ---- fp32 scratch ----
#define OFF_EMB0 0
#define OFF_SA1  24576
#define OFF_SB1  49152
#define OFF_EMB1 73728
#define OFF_SA2  122880
#define OFF_SB2  147456
__device__ float g_ws[172032];
__device__ float g_agg[160];
__device__ int   g_cnt;
__device__ int   g_isf;

struct Ptrs { const void* p[28]; };

__device__ __forceinline__ float b2f(bf16 v){ return __bfloat162float(v); }
__device__ __forceinline__ float LD(const void* p, int i, int f32){
  return f32 ? ((const float*)p)[i] : b2f(((const bf16*)p)[i]);
}
__device__ __forceinline__ int detect_f32(const void* f){
  float v = ((const float*)f)[0];
  return (fabsf(v - 3.14159265f) < 0.01f) ? 1 : 0;
}
__device__ __forceinline__ float fast_rcp(float x){ return __builtin_amdgcn_rcpf(x); }
__device__ __forceinline__ float silu_f(float p){ return p * fast_rcp(1.f + __expf(-p)); }
__device__ __forceinline__ unsigned short rne_bf16(float x){
  unsigned int b = __float_as_uint(x);
  return (unsigned short)((b + 0x7fffu + ((b >> 16) & 1u)) >> 16);
}
__device__ __forceinline__ void cv(const void* p, int off, int sz, int gt, int isf){
  for (int i = gt; i < sz; i += 96*256) g_c[off + i] = LD(p, i, isf);
}

// ---------------- K1: convert inputs to fp32 + emb0/SA1/SB1 prep ----------------
__launch_bounds__(256)
__global__ void k_conv_prep(Ptrs P, const int* __restrict__ charges){
  int t = threadIdx.x;
  int gt = blockIdx.x*256 + t;
  int isf = detect_f32(P.p[2]);
  if (gt == 0){ g_isf = isf; g_cnt = 0; }
  if (gt < 160) g_agg[gt] = 0.f;

  cv(P.p[0],  C_NUC,   2304, gt, isf);
  cv(P.p[2],  C_F,     32,   gt, isf);
  cv(P.p[4],  C_MP1W0, 3072, gt, isf);
  cv(P.p[5],  C_MP1B0, 32,   gt, isf);
  cv(P.p[6],  C_MP1W1, 1024, gt, isf);
  cv(P.p[7],  C_MP1B1, 32,   gt, isf);
  cv(P.p[8],  C_UP1W0, 4096, gt, isf);
  cv(P.p[9],  C_UP1B0, 64,   gt, isf);
  cv(P.p[10], C_UP1W1, 4096, gt, isf);
  cv(P.p[11], C_UP1B1, 64,   gt, isf);
  cv(P.p[12], C_MP2W0, 5120, gt, isf);
  cv(P.p[13], C_MP2B0, 32,   gt, isf);
  cv(P.p[14], C_MP2W1, 1024, gt, isf);
  cv(P.p[15], C_MP2B1, 32,   gt, isf);
  cv(P.p[16], C_UP2W0, 6144, gt, isf);
  cv(P.p[17], C_UP2B0, 64,   gt, isf);
  cv(P.p[18], C_UP2W1, 4096, gt, isf);
  cv(P.p[19], C_UP2B1, 64,   gt, isf);
  cv(P.p[20], C_NOW0,  480,  gt, isf);
  cv(P.p[21], C_NOB0,  3,    gt, isf);
  cv(P.p[22], C_NOW1,  9,    gt, isf);
  cv(P.p[23], C_NOEMB, 30,   gt, isf);
  cv(P.p[24], C_GOW0,  160,  gt, isf);
  cv(P.p[25], C_GOB0,  1,    gt, isf);
  cv(P.p[26], C_GOW1,  1,    gt, isf);
  cv(P.p[27], C_GOB1,  1,    gt, isf);

  __shared__ float w0L[2048];
  __shared__ float rowL[8][32];
  for (int idx = t; idx < 2048; idx += 256) w0L[idx] = LD(P.p[4], idx, isf);
  int nd = t >> 5, col = t & 31;
  int node = blockIdx.x*8 + nd;
  int ch = charges[node];
  float v = LD(P.p[3], ch*32 + col, isf);
  g_ws[OFF_EMB0 + node*32 + col] = v;
  rowL[nd][col] = v;
  __syncthreads();
  float sa = 0.f, sb = 0.f;
  #pragma unroll
  for (int k = 0; k < 32; k++){
    float rv = rowL[nd][k];
    sa = fmaf(rv, w0L[k*32 + col],      sa);
    sb = fmaf(rv, w0L[(32+k)*32 + col], sb);
  }
  g_ws[OFF_SA1 + node*32 + col] = sa;
  g_ws[OFF_SB1 + node*32 + col] = sb;
}

// ---- shared edge-loop macro body: computes msgL[32] for node i ----
#define EDGE_LOOP(SA_OFF, SB_OFF, W0E, B0, W1, B1)                                   \
  {                                                                                  \
    const float* SA = g_ws + (SA_OFF);                                               \
    const float* SB = g_ws + (SB_OFF);                                               \
    {                                                                                \
      const float4* src = (const float4*)(g_c + C_NUC);                              \
      float4* dst = (float4*)pos;                                                    \
      for (int idx = t; idx < 576; idx += 256) dst[idx] = src[idx];                  \
      ((float4*)w1L)[t] = ((const float4*)(g_c + (W1)))[t];                          \
    }                                                                                \
    short8 bfr0, bfr1;                                                               \
    _Pragma("unroll")                                                                \
    for (int j = 0; j < 8; j++){                                                     \
      int row = q*8 + j;                                                             \
      bfr0[j] = (short)rne_bf16(g_c[(W0E) + row*32 + c]);                            \
      bfr1[j] = (short)rne_bf16(g_c[(W0E) + row*32 + 16 + c]);                       \
    }                                                                                \
    float preB0 = SA[i*32 + c]      + g_c[(B0) + c];                                 \
    float preB1 = SA[i*32 + 16 + c] + g_c[(B0) + 16 + c];                            \
    float fj[8];                                                                     \
    _Pragma("unroll")                                                                \
    for (int j = 0; j < 8; j++) fj[j] = g_c[C_F + q*8 + j] * 0.1f;                   \
    __syncthreads();                                                                 \
    float px = pos[i*3], py = pos[i*3+1], pz = pos[i*3+2];                           \
    float sum0 = 0.f, sum1 = 0.f;                                                    \
    for (int tl = w; tl < 48; tl += 4){                                              \
      int el = tl*16 + c;                                                            \
      int ela = (el < NEPS) ? el : 0;                                                \
      int r = ela + (ela >= i);                                                      \
      float dx = px - pos[r*3], dy = py - pos[r*3+1], dz = pz - pos[r*3+2];          \
      float d  = sqrtf(fmaf(dx, dx, fmaf(dy, dy, dz*dz)));                           \
      float xs = d + 1e-8f;                                                          \
      float scv = 0.44721359549995793f * fast_rcp(xs);                               \
      short8 af;                                                                     \
      _Pragma("unroll")                                                              \
      for (int j = 0; j < 8; j++) af[j] = (short)rne_bf16(scv * __sinf(fj[j]*xs));   \
      float4v z = {0.f, 0.f, 0.f, 0.f};                                              \
      float4v a0 = __builtin_amdgcn_mfma_f32_16x16x32_bf16(af, bfr0, z, 0, 0, 0);    \
      float4v a1 = __builtin_amdgcn_mfma_f32_16x16x32_bf16(af, bfr1, z, 0, 0, 0);    \
      _Pragma("unroll")                                                              \
      for (int p = 0; p < 4; p++){                                                   \
        int el2 = tl*16 + q*4 + p;                                                   \
        if (el2 < NEPS){                                                             \
          int r2 = el2 + (el2 >= i);                                                 \
          float v0 = a0[p] + preB0 + SB[r2*32 + c];                                  \
          float v1 = a1[p] + preB1 + SB[r2*32 + 16 + c];                             \
          sum0 += silu_f(v0);                                                        \
          sum1 += silu_f(v1);                                                        \
        }                                                                            \
      }                                                                              \
    }                                                                                \
    sum0 += __shfl_xor(sum0, 16); sum0 += __shfl_xor(sum0, 32);                      \
    sum1 += __shfl_xor(sum1, 16); sum1 += __shfl_xor(sum1, 32);                      \
    if (lane < 16){ wsum[w][lane] = sum0; wsum[w][16 + lane] = sum1; }               \
    __syncthreads();                                                                 \
    if (t < 32) hsumL[t] = wsum[0][t] + wsum[1][t] + wsum[2][t] + wsum[3][t];        \
    __syncthreads();                                                                 \
    if (t < 32){                                                                     \
      float y = 0.f;                                                                 \
      _Pragma("unroll")                                                              \
      for (int m = 0; m < 32; m++) y = fmaf(hsumL[m], w1L[m*32 + t], y);             \
      msgL[t] = y * (1.f/767.f) + g_c[(B1) + t];                                     \
    }                                                                                \
  }

// ---------------- K2: edge pass L1 + fused update-1 + SA2/SB2 ----------------
__launch_bounds__(256)
__global__ void k_edge1(){
  __shared__ __align__(16) float pos[NN*3];
  __shared__ __align__(16) float w1L[1024];
  __shared__ float wsum[4][32];
  __shared__ float hsumL[32];
  __shared__ float msgL[32];
  __shared__ float catU[64];
  __shared__ float hU[64];
  __shared__ float e1U[64];
  __shared__ float part[256];

  int i = blockIdx.x, t = threadIdx.x;
  int w = t >> 6, lane = t & 63, q = lane >> 4, c = lane & 15;

  EDGE_LOOP(OFF_SA1, OFF_SB1, C_MP1W0 + 2048, C_MP1B0, C_MP1W1, C_MP1B1)

  if (t < 32){
    catU[t] = g_ws[OFF_EMB0 + i*32 + t];
    catU[32 + t] = msgL[t];
  }
  __syncthreads();

  // update MLP 1: layer A (64x64)
  int g = t >> 6, col = t & 63;
  {
    const float* w0 = g_c + C_UP1W0;
    float p0 = 0.f;
    #pragma unroll
    for (int j = 0; j < 16; j++){ int k = g*16 + j; p0 = fmaf(catU[k], w0[k*64 + col], p0); }
    part[t] = p0;
  }
  __syncthreads();
  if (t < 64) hU[t] = silu_f(g_c[C_UP1B0 + t] + part[t] + part[64+t] + part[128+t] + part[192+t]);
  __syncthreads();
  // layer B (64x64)
  {
    const float* w1u = g_c + C_UP1W1;
    float p1 = 0.f;
    #pragma unroll
    for (int j = 0; j < 16; j++){ int k = g*16 + j; p1 = fmaf(hU[k], w1u[k*64 + col], p1); }
    part[t] = p1;
  }
  __syncthreads();
  if (t < 64){
    float y = g_c[C_UP1B1 + t] + part[t] + part[64+t] + part[128+t] + part[192+t];
    e1U[t] = y;
    g_ws[OFF_EMB1 + i*64 + t] = y;
  }
  __syncthreads();
  // SA2/SB2 = e1 @ mp2w0[0:64] / mp2w0[64:128]
  {
    int half = t >> 7, g2 = (t >> 5) & 3, c32 = t & 31;
    const float* m2 = g_c + C_MP2W0;
    float p2 = 0.f;
    #pragma unroll
    for (int j = 0; j < 16; j++){
      int k = g2*16 + j;
      p2 = fmaf(e1U[k], m2[(half*64 + k)*32 + c32], p2);
    }
    part[t] = p2;
  }
  __syncthreads();
  if (t < 64){
    int half = t >> 5, c32 = t & 31;
    float s = part[half*128 + c32] + part[half*128 + 32 + c32]
            + part[half*128 + 64 + c32] + part[half*128 + 96 + c32];
    if (half == 0) g_ws[OFF_SA2 + i*32 + c32] = s;
    else           g_ws[OFF_SB2 + i*32 + c32] = s;
  }
}

// ---------------- K3: edge pass L2 + fused update-2 + node_out + global ----------------
__launch_bounds__(256)
__global__ void k_edge2(const int* __restrict__ charges, void* __restrict__ out){
  __shared__ __align__(16) float pos[NN*3];
  __shared__ __align__(16) float w1L[1024];
  __shared__ float wsum[4][32];
  __shared__ float hsumL[32];
  __shared__ float msgL[32];
  __shared__ float catU[96];
  __shared__ float hU[64];
  __shared__ float aggL[160];
  __shared__ float noL[522];
  __shared__ float h3L[3];
  __shared__ float part[256];
  __shared__ int lastL;

  int i = blockIdx.x, t = threadIdx.x;
  int w = t >> 6, lane = t & 63, q = lane >> 4, c = lane & 15;

  EDGE_LOOP(OFF_SA2, OFF_SB2, C_MP2W0 + 4096, C_MP2B0, C_MP2W1, C_MP2B1)

  if (t < 64) catU[t] = g_ws[OFF_EMB1 + i*64 + t];
  if (t < 32){ catU[64 + t] = msgL[t]; aggL[t] = g_ws[OFF_EMB0 + i*32 + t]; }
  for (int idx = t; idx < 522; idx += 256) noL[idx] = g_c[C_NOW0 + idx];
  __syncthreads();

  // update MLP 2: layer A (96x64)
  int g = t >> 6, col = t & 63;
  {
    const float* w0 = g_c + C_UP2W0;
    float p0 = 0.f;
    #pragma unroll
    for (int j = 0; j < 24; j++){ int k = g*24 + j; p0 = fmaf(catU[k], w0[k*64 + col], p0); }
    part[t] = p0;
  }
  __syncthreads();
  if (t < 64) hU[t] = silu_f(g_c[C_UP2B0 + t] + part[t] + part[64+t] + part[128+t] + part[192+t]);
  __syncthreads();
  // layer B (64x64)
  {
    const float* w1u = g_c + C_UP2W1;
    float p1 = 0.f;
    #pragma unroll
    for (int j = 0; j < 16; j++){ int k = g*16 + j; p1 = fmaf(hU[k], w1u[k*64 + col], p1); }
    part[t] = p1;
  }
  __syncthreads();
  if (t < 64){
    float y = g_c[C_UP2B1 + t] + part[t] + part[64+t] + part[128+t] + part[192+t];
    float e2 = catU[t] + y;   // residual
    aggL[32 + t] = catU[t];   // emb1
    aggL[96 + t] = e2;        // emb2
  }
  __syncthreads();
  // node-out MLP: 48 threads compute 16x3 partials over k=160
  if (t < 48){
    int chunk = t / 3, c3 = t - chunk*3;
    float p = 0.f;
    #pragma unroll
    for (int j = 0; j < 10; j++){ int k = chunk*10 + j; p = fmaf(aggL[k], noL[k*3 + c3], p); }
    part[t] = p;
  }
  __syncthreads();
  if (t < 3){
    float p = noL[480 + t];
    #pragma unroll
    for (int ch = 0; ch < 16; ch++) p += part[ch*3 + t];
    h3L[t] = silu_f(p);
  }
  __syncthreads();
  if (t < 3){
    float o = 0.f;
    #pragma unroll
    for (int m = 0; m < 3; m++) o = fmaf(h3L[m], noL[483 + m*3 + t], o);
    o += noL[492 + charges[i]*3 + t];
    if (g_isf) ((float*)out)[i*3 + t] = o;
    else       ((bf16*)out)[i*3 + t] = __float2bfloat16(o);
  }
  // global aggregation
  if (t < 160) atomicAdd(&g_agg[t], aggL[t]);
  __threadfence();
  __syncthreads();
  if (t == 0) lastL = (atomicAdd(&g_cnt, 1) == NN - 1) ? 1 : 0;
  __syncthreads();
  if (lastL){
    float v = 0.f;
    if (t < 160) v = atomicAdd(&g_agg[t], 0.f) * (1.f/768.f) * g_c[C_GOW0 + t];
    part[t] = v;
    __syncthreads();
    if (t == 0){
      float tot = 0.f;
      for (int k = 0; k < 160; k++) tot += part[k];
      float h = silu_f(tot + g_c[C_GOB0]);
      float go = h * g_c[C_GOW1] + g_c[C_GOB1];
      if (g_isf) ((float*)out)[2304] = go;
      else       ((bf16*)out)[2304] = __float2bfloat16(go);
    }
  }
}

extern "C" void kernel_launch(void* const* d_in, const int* in_sizes, int n_in,
                              void* d_out, int out_size, void* d_ws, size_t ws_size,
                              hipStream_t stream) {
  Ptrs P;
  for (int k = 0; k < 28; k++) P.p[k] = d_in[k];
  const int* charges = (const int*)d_in[1];

  k_conv_prep<<<96, 256, 0, stream>>>(P, charges);
  k_edge1<<<NN, 256, 0, stream>>>();
  k_edge2<<<NN, 256, 0, stream>>>(charges, d_out);
}

// Round 6
// 178.578 us; speedup vs baseline: 1.2386x; 1.2386x over previous
//
#include <hip/hip_runtime.h>
#include <hip/hip_bf16.h>

typedef __hip_bfloat16 bf16;
typedef __attribute__((ext_vector_type(8))) short short8;
typedef __attribute__((ext_vector_type(4))) float float4v;

#define NN   768
#define NEPS 767

// ---- converted fp32 constants ----
#define C_NUC   0
#define C_F     2304
#define C_MP1W0 2656
#define C_MP1B0 5728
#define C_MP1W1 5760
#define C_MP1B1 6784
#define C_UP1W0 6816
#define C_UP1B0 10912
#define C_UP1W1 10976
#define C_UP1B1 15072
#define C_MP2W0 15136
#define C_MP2B0 20256
#define C_MP2W1 20288
#define C_MP2B1 21312
#define C_UP2W0 21344
#define C_UP2B0 27488
#define C_UP2W1 27552
#define C_UP2B1 31648
#define C_NOW0  31712
#define C_NOB0  32192
#define C_NOW1  32195
#define C_NOEMB 32204
#define C_GOW0  32234
#define C_GOB0  32394
#define C_GOW1  32395
#define C_GOB1  32396
__device__ __align__(16) float g_c[32400];

// ---- fp32 scratch ----
#define OFF_EMB0 0
#define OFF_SA1  24576
#define OFF_SB1  49152
#define OFF_EMB1 73728
#define OFF_SA2  122880
#define OFF_SB2  147456
__device__ float g_ws[172032];
__device__ float g_agg[640];     // 4 replicas x 160 (contention spread)
__device__ int   g_cnt;
__device__ int   g_isf;

struct Ptrs { const void* p[28]; };

__device__ __forceinline__ float b2f(bf16 v){ return __bfloat162float(v); }
__device__ __forceinline__ float LD(const void* p, int i, int f32){
  return f32 ? ((const float*)p)[i] : b2f(((const bf16*)p)[i]);
}
__device__ __forceinline__ int detect_f32(const void* f){
  float v = ((const float*)f)[0];
  return (fabsf(v - 3.14159265f) < 0.01f) ? 1 : 0;
}
__device__ __forceinline__ float fast_rcp(float x){ return __builtin_amdgcn_rcpf(x); }
__device__ __forceinline__ float silu_f(float p){ return p * fast_rcp(1.f + __expf(-p)); }
__device__ __forceinline__ unsigned short rne_bf16(float x){
  unsigned int b = __float_as_uint(x);
  return (unsigned short)((b + 0x7fffu + ((b >> 16) & 1u)) >> 16);
}
__device__ __forceinline__ void cv(const void* p, int off, int sz, int gt, int isf){
  for (int i = gt; i < sz; i += 96*256) g_c[off + i] = LD(p, i, isf);
}

// ---------------- K1: convert inputs to fp32 + emb0/SA1/SB1 prep ----------------
__launch_bounds__(256)
__global__ void k_conv_prep(Ptrs P, const int* __restrict__ charges){
  int t = threadIdx.x;
  int gt = blockIdx.x*256 + t;
  int isf = detect_f32(P.p[2]);
  if (gt == 0){ g_isf = isf; g_cnt = 0; }
  if (gt < 640) g_agg[gt] = 0.f;

  cv(P.p[0],  C_NUC,   2304, gt, isf);
  cv(P.p[2],  C_F,     32,   gt, isf);
  cv(P.p[4],  C_MP1W0, 3072, gt, isf);
  cv(P.p[5],  C_MP1B0, 32,   gt, isf);
  cv(P.p[6],  C_MP1W1, 1024, gt, isf);
  cv(P.p[7],  C_MP1B1, 32,   gt, isf);
  cv(P.p[8],  C_UP1W0, 4096, gt, isf);
  cv(P.p[9],  C_UP1B0, 64,   gt, isf);
  cv(P.p[10], C_UP1W1, 4096, gt, isf);
  cv(P.p[11], C_UP1B1, 64,   gt, isf);
  cv(P.p[12], C_MP2W0, 5120, gt, isf);
  cv(P.p[13], C_MP2B0, 32,   gt, isf);
  cv(P.p[14], C_MP2W1, 1024, gt, isf);
  cv(P.p[15], C_MP2B1, 32,   gt, isf);
  cv(P.p[16], C_UP2W0, 6144, gt, isf);
  cv(P.p[17], C_UP2B0, 64,   gt, isf);
  cv(P.p[18], C_UP2W1, 4096, gt, isf);
  cv(P.p[19], C_UP2B1, 64,   gt, isf);
  cv(P.p[20], C_NOW0,  480,  gt, isf);
  cv(P.p[21], C_NOB0,  3,    gt, isf);
  cv(P.p[22], C_NOW1,  9,    gt, isf);
  cv(P.p[23], C_NOEMB, 30,   gt, isf);
  cv(P.p[24], C_GOW0,  160,  gt, isf);
  cv(P.p[25], C_GOB0,  1,    gt, isf);
  cv(P.p[26], C_GOW1,  1,    gt, isf);
  cv(P.p[27], C_GOB1,  1,    gt, isf);

  __shared__ float w0L[2048];
  __shared__ float rowL[8][32];
  for (int idx = t; idx < 2048; idx += 256) w0L[idx] = LD(P.p[4], idx, isf);
  int nd = t >> 5, col = t & 31;
  int node = blockIdx.x*8 + nd;
  int ch = charges[node];
  float v = LD(P.p[3], ch*32 + col, isf);
  g_ws[OFF_EMB0 + node*32 + col] = v;
  rowL[nd][col] = v;
  __syncthreads();
  float sa = 0.f, sb = 0.f;
  #pragma unroll
  for (int k = 0; k < 32; k++){
    float rv = rowL[nd][k];
    sa = fmaf(rv, w0L[k*32 + col],      sa);
    sb = fmaf(rv, w0L[(32+k)*32 + col], sb);
  }
  g_ws[OFF_SA1 + node*32 + col] = sa;
  g_ws[OFF_SB1 + node*32 + col] = sb;
}

// ---- shared edge-loop macro body: computes msgL[32] for node i ----
#define EDGE_LOOP(SA_OFF, SB_OFF, W0E, B0, W1, B1)                                   \
  {                                                                                  \
    const float* SA = g_ws + (SA_OFF);                                               \
    const float* SB = g_ws + (SB_OFF);                                               \
    {                                                                                \
      const float4* src = (const float4*)(g_c + C_NUC);                              \
      float4* dst = (float4*)pos;                                                    \
      for (int idx = t; idx < 576; idx += 256) dst[idx] = src[idx];                  \
      ((float4*)w1L)[t] = ((const float4*)(g_c + (W1)))[t];                          \
    }                                                                                \
    short8 bfr0, bfr1;                                                               \
    _Pragma("unroll")                                                                \
    for (int j = 0; j < 8; j++){                                                     \
      int row = q*8 + j;                                                             \
      bfr0[j] = (short)rne_bf16(g_c[(W0E) + row*32 + c]);                            \
      bfr1[j] = (short)rne_bf16(g_c[(W0E) + row*32 + 16 + c]);                       \
    }                                                                                \
    float preB0 = SA[i*32 + c]      + g_c[(B0) + c];                                 \
    float preB1 = SA[i*32 + 16 + c] + g_c[(B0) + 16 + c];                            \
    float fj[8];                                                                     \
    _Pragma("unroll")                                                                \
    for (int j = 0; j < 8; j++) fj[j] = g_c[C_F + q*8 + j] * 0.1f;                   \
    __syncthreads();                                                                 \
    float px = pos[i*3], py = pos[i*3+1], pz = pos[i*3+2];                           \
    float sum0 = 0.f, sum1 = 0.f;                                                    \
    for (int tl = w; tl < 48; tl += 4){                                              \
      int el = tl*16 + c;                                                            \
      int ela = (el < NEPS) ? el : 0;                                                \
      int r = ela + (ela >= i);                                                      \
      float dx = px - pos[r*3], dy = py - pos[r*3+1], dz = pz - pos[r*3+2];          \
      float d  = sqrtf(fmaf(dx, dx, fmaf(dy, dy, dz*dz)));                           \
      float xs = d + 1e-8f;                                                          \
      float scv = 0.44721359549995793f * fast_rcp(xs);                               \
      short8 af;                                                                     \
      _Pragma("unroll")                                                              \
      for (int j = 0; j < 8; j++) af[j] = (short)rne_bf16(scv * __sinf(fj[j]*xs));   \
      float4v z = {0.f, 0.f, 0.f, 0.f};                                              \
      float4v a0 = __builtin_amdgcn_mfma_f32_16x16x32_bf16(af, bfr0, z, 0, 0, 0);    \
      float4v a1 = __builtin_amdgcn_mfma_f32_16x16x32_bf16(af, bfr1, z, 0, 0, 0);    \
      _Pragma("unroll")                                                              \
      for (int p = 0; p < 4; p++){                                                   \
        int el2 = tl*16 + q*4 + p;                                                   \
        if (el2 < NEPS){                                                             \
          int r2 = el2 + (el2 >= i);                                                 \
          float v0 = a0[p] + preB0 + SB[r2*32 + c];                                  \
          float v1 = a1[p] + preB1 + SB[r2*32 + 16 + c];                             \
          sum0 += silu_f(v0);                                                        \
          sum1 += silu_f(v1);                                                        \
        }                                                                            \
      }                                                                              \
    }                                                                                \
    sum0 += __shfl_xor(sum0, 16); sum0 += __shfl_xor(sum0, 32);                      \
    sum1 += __shfl_xor(sum1, 16); sum1 += __shfl_xor(sum1, 32);                      \
    if (lane < 16){ wsum[w][lane] = sum0; wsum[w][16 + lane] = sum1; }               \
    __syncthreads();                                                                 \
    if (t < 32) hsumL[t] = wsum[0][t] + wsum[1][t] + wsum[2][t] + wsum[3][t];        \
    __syncthreads();                                                                 \
    if (t < 32){                                                                     \
      float y = 0.f;                                                                 \
      _Pragma("unroll")                                                              \
      for (int m = 0; m < 32; m++) y = fmaf(hsumL[m], w1L[m*32 + t], y);             \
      msgL[t] = y * (1.f/767.f) + g_c[(B1) + t];                                     \
    }                                                                                \
  }

// ---------------- K2: edge pass L1 + fused update-1 + SA2/SB2 ----------------
__launch_bounds__(256)
__global__ void k_edge1(){
  __shared__ __align__(16) float pos[NN*3];
  __shared__ __align__(16) float w1L[1024];
  __shared__ float wsum[4][32];
  __shared__ float hsumL[32];
  __shared__ float msgL[32];
  __shared__ float catU[64];
  __shared__ float hU[64];
  __shared__ float e1U[64];
  __shared__ float part[256];

  int i = blockIdx.x, t = threadIdx.x;
  int w = t >> 6, lane = t & 63, q = lane >> 4, c = lane & 15;

  EDGE_LOOP(OFF_SA1, OFF_SB1, C_MP1W0 + 2048, C_MP1B0, C_MP1W1, C_MP1B1)

  if (t < 32){
    catU[t] = g_ws[OFF_EMB0 + i*32 + t];
    catU[32 + t] = msgL[t];
  }
  __syncthreads();

  // update MLP 1: layer A (64x64)
  int g = t >> 6, col = t & 63;
  {
    const float* w0 = g_c + C_UP1W0;
    float p0 = 0.f;
    #pragma unroll
    for (int j = 0; j < 16; j++){ int k = g*16 + j; p0 = fmaf(catU[k], w0[k*64 + col], p0); }
    part[t] = p0;
  }
  __syncthreads();
  if (t < 64) hU[t] = silu_f(g_c[C_UP1B0 + t] + part[t] + part[64+t] + part[128+t] + part[192+t]);
  __syncthreads();
  // layer B (64x64)
  {
    const float* w1u = g_c + C_UP1W1;
    float p1 = 0.f;
    #pragma unroll
    for (int j = 0; j < 16; j++){ int k = g*16 + j; p1 = fmaf(hU[k], w1u[k*64 + col], p1); }
    part[t] = p1;
  }
  __syncthreads();
  if (t < 64){
    float y = g_c[C_UP1B1 + t] + part[t] + part[64+t] + part[128+t] + part[192+t];
    e1U[t] = y;
    g_ws[OFF_EMB1 + i*64 + t] = y;
  }
  __syncthreads();
  // SA2/SB2 = e1 @ mp2w0[0:64] / mp2w0[64:128]
  {
    int half = t >> 7, g2 = (t >> 5) & 3, c32 = t & 31;
    const float* m2 = g_c + C_MP2W0;
    float p2 = 0.f;
    #pragma unroll
    for (int j = 0; j < 16; j++){
      int k = g2*16 + j;
      p2 = fmaf(e1U[k], m2[(half*64 + k)*32 + c32], p2);
    }
    part[t] = p2;
  }
  __syncthreads();
  if (t < 64){
    int half = t >> 5, c32 = t & 31;
    float s = part[half*128 + c32] + part[half*128 + 32 + c32]
            + part[half*128 + 64 + c32] + part[half*128 + 96 + c32];
    if (half == 0) g_ws[OFF_SA2 + i*32 + c32] = s;
    else           g_ws[OFF_SB2 + i*32 + c32] = s;
  }
}

// ---------------- K3: edge pass L2 + fused update-2 + node_out + global ----------------
__launch_bounds__(256)
__global__ void k_edge2(const int* __restrict__ charges, void* __restrict__ out){
  __shared__ __align__(16) float pos[NN*3];
  __shared__ __align__(16) float w1L[1024];
  __shared__ float wsum[4][32];
  __shared__ float hsumL[32];
  __shared__ float msgL[32];
  __shared__ float catU[96];
  __shared__ float hU[64];
  __shared__ float aggL[160];
  __shared__ float noL[522];
  __shared__ float h3L[3];
  __shared__ float part[256];
  __shared__ int lastL;

  int i = blockIdx.x, t = threadIdx.x;
  int w = t >> 6, lane = t & 63, q = lane >> 4, c = lane & 15;

  EDGE_LOOP(OFF_SA2, OFF_SB2, C_MP2W0 + 4096, C_MP2B0, C_MP2W1, C_MP2B1)

  if (t < 64) catU[t] = g_ws[OFF_EMB1 + i*64 + t];
  if (t < 32){ catU[64 + t] = msgL[t]; aggL[t] = g_ws[OFF_EMB0 + i*32 + t]; }
  for (int idx = t; idx < 522; idx += 256) noL[idx] = g_c[C_NOW0 + idx];
  __syncthreads();

  // update MLP 2: layer A (96x64)
  int g = t >> 6, col = t & 63;
  {
    const float* w0 = g_c + C_UP2W0;
    float p0 = 0.f;
    #pragma unroll
    for (int j = 0; j < 24; j++){ int k = g*24 + j; p0 = fmaf(catU[k], w0[k*64 + col], p0); }
    part[t] = p0;
  }
  __syncthreads();
  if (t < 64) hU[t] = silu_f(g_c[C_UP2B0 + t] + part[t] + part[64+t] + part[128+t] + part[192+t]);
  __syncthreads();
  // layer B (64x64)
  {
    const float* w1u = g_c + C_UP2W1;
    float p1 = 0.f;
    #pragma unroll
    for (int j = 0; j < 16; j++){ int k = g*16 + j; p1 = fmaf(hU[k], w1u[k*64 + col], p1); }
    part[t] = p1;
  }
  __syncthreads();
  if (t < 64){
    float y = g_c[C_UP2B1 + t] + part[t] + part[64+t] + part[128+t] + part[192+t];
    float e2 = catU[t] + y;   // residual
    aggL[32 + t] = catU[t];   // emb1
    aggL[96 + t] = e2;        // emb2
  }
  __syncthreads();
  // node-out MLP: 48 threads compute 16x3 partials over k=160
  if (t < 48){
    int chunk = t / 3, c3 = t - chunk*3;
    float p = 0.f;
    #pragma unroll
    for (int j = 0; j < 10; j++){ int k = chunk*10 + j; p = fmaf(aggL[k], noL[k*3 + c3], p); }
    part[t] = p;
  }
  __syncthreads();
  if (t < 3){
    float p = noL[480 + t];
    #pragma unroll
    for (int ch = 0; ch < 16; ch++) p += part[ch*3 + t];
    h3L[t] = silu_f(p);
  }
  __syncthreads();
  if (t < 3){
    float o = 0.f;
    #pragma unroll
    for (int m = 0; m < 3; m++) o = fmaf(h3L[m], noL[483 + m*3 + t], o);
    o += noL[492 + charges[i]*3 + t];
    if (g_isf) ((float*)out)[i*3 + t] = o;
    else       ((bf16*)out)[i*3 + t] = __float2bfloat16(o);
  }
  // global aggregation: 4-way replicated atomics; NO __threadfence.
  // Ordering: __syncthreads() drains vmcnt(0) -> all g_agg atomics performed at
  // the device coherence point before t0's g_cnt atomic is issued.
  if (t < 160) atomicAdd(&g_agg[(i & 3)*160 + t], aggL[t]);
  __syncthreads();
  if (t == 0) lastL = (atomicAdd(&g_cnt, 1) == NN - 1) ? 1 : 0;
  __syncthreads();
  if (lastL){
    float v = 0.f;
    if (t < 160){
      float s = atomicAdd(&g_agg[t], 0.f) + atomicAdd(&g_agg[160 + t], 0.f)
              + atomicAdd(&g_agg[320 + t], 0.f) + atomicAdd(&g_agg[480 + t], 0.f);
      v = s * (1.f/768.f) * g_c[C_GOW0 + t];
    }
    part[t] = v;
    __syncthreads();
    if (t == 0){
      float tot = 0.f;
      for (int k = 0; k < 160; k++) tot += part[k];
      float h = silu_f(tot + g_c[C_GOB0]);
      float go = h * g_c[C_GOW1] + g_c[C_GOB1];
      if (g_isf) ((float*)out)[2304] = go;
      else       ((bf16*)out)[2304] = __float2bfloat16(go);
    }
  }
}

extern "C" void kernel_launch(void* const* d_in, const int* in_sizes, int n_in,
                              void* d_out, int out_size, void* d_ws, size_t ws_size,
                              hipStream_t stream) {
  Ptrs P;
  for (int k = 0; k < 28; k++) P.p[k] = d_in[k];
  const int* charges = (const int*)d_in[1];

  k_conv_prep<<<96, 256, 0, stream>>>(P, charges);
  k_edge1<<<NN, 256, 0, stream>>>();
  k_edge2<<<NN, 256, 0, stream>>>(charges, d_out);
}

// Round 7
// 164.751 us; speedup vs baseline: 1.3425x; 1.0839x over previous
//
#include <hip/hip_runtime.h>
#include <hip/hip_bf16.h>

typedef __hip_bfloat16 bf16;
typedef __attribute__((ext_vector_type(8))) short short8;
typedef __attribute__((ext_vector_type(4))) float float4v;

#define NN   768
#define NEPS 767

// ---- converted fp32 constants ----
#define C_NUC   0
#define C_F     2304
#define C_MP1W0 2656
#define C_MP1B0 5728
#define C_MP1W1 5760
#define C_MP1B1 6784
#define C_UP1W0 6816
#define C_UP1B0 10912
#define C_UP1W1 10976
#define C_UP1B1 15072
#define C_MP2W0 15136
#define C_MP2B0 20256
#define C_MP2W1 20288
#define C_MP2B1 21312
#define C_UP2W0 21344
#define C_UP2B0 27488
#define C_UP2W1 27552
#define C_UP2B1 31648
#define C_NOW0  31712
#define C_NOB0  32192
#define C_NOW1  32195
#define C_NOEMB 32204
#define C_GOW0  32234
#define C_GOB0  32394
#define C_GOW1  32395
#define C_GOB1  32396
__device__ __align__(16) float g_c[32400];

// ---- fp32 scratch ----
#define OFF_EMB0 0
#define OFF_SA1  24576
#define OFF_SB1  49152
#define OFF_EMB1 73728
#define OFF_SA2  122880
#define OFF_SB2  147456
__device__ float g_ws[172032];
__device__ float g_agg[640];     // 4 replicas x 160
__device__ int   g_cnt;
__device__ int   g_isf;
// RBF A-fragments, reused by both edge passes: [node][tile][lane] -> short8
__device__ short8 g_rbf[NN*48*64];

struct Ptrs { const void* p[28]; };

__device__ __forceinline__ float b2f(bf16 v){ return __bfloat162float(v); }
__device__ __forceinline__ float LD(const void* p, int i, int f32){
  return f32 ? ((const float*)p)[i] : b2f(((const bf16*)p)[i]);
}
__device__ __forceinline__ int detect_f32(const void* f){
  float v = ((const float*)f)[0];
  return (fabsf(v - 3.14159265f) < 0.01f) ? 1 : 0;
}
__device__ __forceinline__ float fast_rcp(float x){ return __builtin_amdgcn_rcpf(x); }
__device__ __forceinline__ float silu_f(float p){ return p * fast_rcp(1.f + __expf(-p)); }
__device__ __forceinline__ unsigned short rne_bf16(float x){
  unsigned int b = __float_as_uint(x);
  return (unsigned short)((b + 0x7fffu + ((b >> 16) & 1u)) >> 16);
}
__device__ __forceinline__ void cv(const void* p, int off, int sz, int gt, int isf){
  for (int i = gt; i < sz; i += 96*256) g_c[off + i] = LD(p, i, isf);
}

// ---------------- K1: convert inputs to fp32 + emb0/SA1/SB1 prep ----------------
__launch_bounds__(256)
__global__ void k_conv_prep(Ptrs P, const int* __restrict__ charges){
  int t = threadIdx.x;
  int gt = blockIdx.x*256 + t;
  int isf = detect_f32(P.p[2]);
  if (gt == 0){ g_isf = isf; g_cnt = 0; }
  if (gt < 640) g_agg[gt] = 0.f;

  cv(P.p[0],  C_NUC,   2304, gt, isf);
  cv(P.p[2],  C_F,     32,   gt, isf);
  cv(P.p[4],  C_MP1W0, 3072, gt, isf);
  cv(P.p[5],  C_MP1B0, 32,   gt, isf);
  cv(P.p[6],  C_MP1W1, 1024, gt, isf);
  cv(P.p[7],  C_MP1B1, 32,   gt, isf);
  cv(P.p[8],  C_UP1W0, 4096, gt, isf);
  cv(P.p[9],  C_UP1B0, 64,   gt, isf);
  cv(P.p[10], C_UP1W1, 4096, gt, isf);
  cv(P.p[11], C_UP1B1, 64,   gt, isf);
  cv(P.p[12], C_MP2W0, 5120, gt, isf);
  cv(P.p[13], C_MP2B0, 32,   gt, isf);
  cv(P.p[14], C_MP2W1, 1024, gt, isf);
  cv(P.p[15], C_MP2B1, 32,   gt, isf);
  cv(P.p[16], C_UP2W0, 6144, gt, isf);
  cv(P.p[17], C_UP2B0, 64,   gt, isf);
  cv(P.p[18], C_UP2W1, 4096, gt, isf);
  cv(P.p[19], C_UP2B1, 64,   gt, isf);
  cv(P.p[20], C_NOW0,  480,  gt, isf);
  cv(P.p[21], C_NOB0,  3,    gt, isf);
  cv(P.p[22], C_NOW1,  9,    gt, isf);
  cv(P.p[23], C_NOEMB, 30,   gt, isf);
  cv(P.p[24], C_GOW0,  160,  gt, isf);
  cv(P.p[25], C_GOB0,  1,    gt, isf);
  cv(P.p[26], C_GOW1,  1,    gt, isf);
  cv(P.p[27], C_GOB1,  1,    gt, isf);

  __shared__ float w0L[2048];
  __shared__ float rowL[8][32];
  for (int idx = t; idx < 2048; idx += 256) w0L[idx] = LD(P.p[4], idx, isf);
  int nd = t >> 5, col = t & 31;
  int node = blockIdx.x*8 + nd;
  int ch = charges[node];
  float v = LD(P.p[3], ch*32 + col, isf);
  g_ws[OFF_EMB0 + node*32 + col] = v;
  rowL[nd][col] = v;
  __syncthreads();
  float sa = 0.f, sb = 0.f;
  #pragma unroll
  for (int k = 0; k < 32; k++){
    float rv = rowL[nd][k];
    sa = fmaf(rv, w0L[k*32 + col],      sa);
    sb = fmaf(rv, w0L[(32+k)*32 + col], sb);
  }
  g_ws[OFF_SA1 + node*32 + col] = sa;
  g_ws[OFF_SB1 + node*32 + col] = sb;
}

// ---------------- K2: edge pass L1 (computes+stores RBF) + fused update-1 ----------------
__launch_bounds__(256)
__global__ void k_edge1(){
  __shared__ __align__(16) float pos[NN*3];
  __shared__ __align__(16) float w1L[1024];
  __shared__ float wsum[4][32];
  __shared__ float hsumL[32];
  __shared__ float msgL[32];
  __shared__ float catU[64], hU[64], e1U[64], part[256];

  int i = blockIdx.x, t = threadIdx.x;
  int w = t >> 6, lane = t & 63, q = lane >> 4, c = lane & 15;

  {
    const float4* src = (const float4*)(g_c + C_NUC);
    float4* dst = (float4*)pos;
    for (int idx = t; idx < 576; idx += 256) dst[idx] = src[idx];
    ((float4*)w1L)[t] = ((const float4*)(g_c + C_MP1W1))[t];
  }
  const float* SA = g_ws + OFF_SA1;
  const float* SB = g_ws + OFF_SB1;
  short8 bfr0, bfr1;
  #pragma unroll
  for (int j = 0; j < 8; j++){
    int row = q*8 + j;
    bfr0[j] = (short)rne_bf16(g_c[C_MP1W0 + 2048 + row*32 + c]);
    bfr1[j] = (short)rne_bf16(g_c[C_MP1W0 + 2048 + row*32 + 16 + c]);
  }
  float preB0 = SA[i*32 + c]      + g_c[C_MP1B0 + c];
  float preB1 = SA[i*32 + 16 + c] + g_c[C_MP1B0 + 16 + c];
  float fj[8];
  #pragma unroll
  for (int j = 0; j < 8; j++) fj[j] = g_c[C_F + q*8 + j] * 0.1f;
  __syncthreads();

  float px = pos[i*3], py = pos[i*3+1], pz = pos[i*3+2];

  // batch all 12 distances (independent ds_reads pipeline)
  float xs[12], scv[12];
  #pragma unroll
  for (int s = 0; s < 12; s++){
    int el = (w + s*4)*16 + c;
    int ela = (el < NEPS) ? el : 0;
    int r = ela + (ela >= i);
    float dx = px - pos[r*3], dy = py - pos[r*3+1], dz = pz - pos[r*3+2];
    float d = sqrtf(fmaf(dx, dx, fmaf(dy, dy, dz*dz)));
    xs[s] = d + 1e-8f;
    scv[s] = 0.44721359549995793f * fast_rcp(xs[s]);
  }

  float sum0 = 0.f, sum1 = 0.f;
  #pragma unroll 4
  for (int s = 0; s < 12; s++){
    int tl = w + s*4;
    // SB prefetch: issued before the sin chain (~150cyc cover)
    float sb0[4], sb1[4];
    #pragma unroll
    for (int p = 0; p < 4; p++){
      int el2 = tl*16 + q*4 + p;
      int e2a = (el2 < NEPS) ? el2 : 0;
      int r2 = e2a + (e2a >= i);
      sb0[p] = SB[r2*32 + c];
      sb1[p] = SB[r2*32 + 16 + c];
    }
    short8 af;
    #pragma unroll
    for (int j = 0; j < 8; j++) af[j] = (short)rne_bf16(scv[s] * __sinf(fj[j]*xs[s]));
    g_rbf[(i*48 + tl)*64 + lane] = af;   // coalesced dwordx4, reused by k_edge2
    float4v z = {0.f, 0.f, 0.f, 0.f};
    float4v a0 = __builtin_amdgcn_mfma_f32_16x16x32_bf16(af, bfr0, z, 0, 0, 0);
    float4v a1 = __builtin_amdgcn_mfma_f32_16x16x32_bf16(af, bfr1, z, 0, 0, 0);
    #pragma unroll
    for (int p = 0; p < 4; p++){
      int el2 = tl*16 + q*4 + p;
      if (el2 < NEPS){
        sum0 += silu_f(a0[p] + preB0 + sb0[p]);
        sum1 += silu_f(a1[p] + preB1 + sb1[p]);
      }
    }
  }
  sum0 += __shfl_xor(sum0, 16); sum0 += __shfl_xor(sum0, 32);
  sum1 += __shfl_xor(sum1, 16); sum1 += __shfl_xor(sum1, 32);
  if (lane < 16){ wsum[w][lane] = sum0; wsum[w][16 + lane] = sum1; }
  __syncthreads();
  if (t < 32) hsumL[t] = wsum[0][t] + wsum[1][t] + wsum[2][t] + wsum[3][t];
  __syncthreads();
  if (t < 32){
    float y = 0.f;
    #pragma unroll
    for (int m = 0; m < 32; m++) y = fmaf(hsumL[m], w1L[m*32 + t], y);
    msgL[t] = y * (1.f/767.f) + g_c[C_MP1B1 + t];
  }

  if (t < 32){
    catU[t] = g_ws[OFF_EMB0 + i*32 + t];
    catU[32 + t] = msgL[t];
  }
  __syncthreads();

  // update MLP 1: layer A (64x64)
  int g = t >> 6, col = t & 63;
  {
    const float* w0 = g_c + C_UP1W0;
    float p0 = 0.f;
    #pragma unroll
    for (int j = 0; j < 16; j++){ int k = g*16 + j; p0 = fmaf(catU[k], w0[k*64 + col], p0); }
    part[t] = p0;
  }
  __syncthreads();
  if (t < 64) hU[t] = silu_f(g_c[C_UP1B0 + t] + part[t] + part[64+t] + part[128+t] + part[192+t]);
  __syncthreads();
  {
    const float* w1u = g_c + C_UP1W1;
    float p1 = 0.f;
    #pragma unroll
    for (int j = 0; j < 16; j++){ int k = g*16 + j; p1 = fmaf(hU[k], w1u[k*64 + col], p1); }
    part[t] = p1;
  }
  __syncthreads();
  if (t < 64){
    float y = g_c[C_UP1B1 + t] + part[t] + part[64+t] + part[128+t] + part[192+t];
    e1U[t] = y;
    g_ws[OFF_EMB1 + i*64 + t] = y;
  }
  __syncthreads();
  {
    int half = t >> 7, g2 = (t >> 5) & 3, c32 = t & 31;
    const float* m2 = g_c + C_MP2W0;
    float p2 = 0.f;
    #pragma unroll
    for (int j = 0; j < 16; j++){
      int k = g2*16 + j;
      p2 = fmaf(e1U[k], m2[(half*64 + k)*32 + c32], p2);
    }
    part[t] = p2;
  }
  __syncthreads();
  if (t < 64){
    int half = t >> 5, c32 = t & 31;
    float s = part[half*128 + c32] + part[half*128 + 32 + c32]
            + part[half*128 + 64 + c32] + part[half*128 + 96 + c32];
    if (half == 0) g_ws[OFF_SA2 + i*32 + c32] = s;
    else           g_ws[OFF_SB2 + i*32 + c32] = s;
  }
}

// ---------------- K3: edge pass L2 (loads RBF) + fused update-2 + outputs ----------------
__launch_bounds__(256)
__global__ void k_edge2(const int* __restrict__ charges, void* __restrict__ out){
  __shared__ __align__(16) float w1L[1024];
  __shared__ float wsum[4][32];
  __shared__ float hsumL[32];
  __shared__ float msgL[32];
  __shared__ float catU[96], hU[64], aggL[160], noL[522], h3L[3], part[256];
  __shared__ int lastL;

  int i = blockIdx.x, t = threadIdx.x;
  int w = t >> 6, lane = t & 63, q = lane >> 4, c = lane & 15;

  ((float4*)w1L)[t] = ((const float4*)(g_c + C_MP2W1))[t];
  const float* SA = g_ws + OFF_SA2;
  const float* SB = g_ws + OFF_SB2;
  short8 bfr0, bfr1;
  #pragma unroll
  for (int j = 0; j < 8; j++){
    int row = q*8 + j;
    bfr0[j] = (short)rne_bf16(g_c[C_MP2W0 + 4096 + row*32 + c]);
    bfr1[j] = (short)rne_bf16(g_c[C_MP2W0 + 4096 + row*32 + 16 + c]);
  }
  float preB0 = SA[i*32 + c]      + g_c[C_MP2B0 + c];
  float preB1 = SA[i*32 + 16 + c] + g_c[C_MP2B0 + 16 + c];

  // double-buffered pipeline over 12 tiles: load s+1 while consuming s
  float sum0 = 0.f, sum1 = 0.f;
  short8 afA = g_rbf[(i*48 + w)*64 + lane];
  float sbA0[4], sbA1[4];
  #pragma unroll
  for (int p = 0; p < 4; p++){
    int el2 = w*16 + q*4 + p;
    int e2a = (el2 < NEPS) ? el2 : 0;
    int r2 = e2a + (e2a >= i);
    sbA0[p] = SB[r2*32 + c];
    sbA1[p] = SB[r2*32 + 16 + c];
  }
  #pragma unroll
  for (int s = 0; s < 12; s++){
    int tl = w + s*4;
    short8 afB;
    float sbB0[4], sbB1[4];
    if (s < 11){
      int tn = tl + 4;
      afB = g_rbf[(i*48 + tn)*64 + lane];
      #pragma unroll
      for (int p = 0; p < 4; p++){
        int el2 = tn*16 + q*4 + p;
        int e2a = (el2 < NEPS) ? el2 : 0;
        int r2 = e2a + (e2a >= i);
        sbB0[p] = SB[r2*32 + c];
        sbB1[p] = SB[r2*32 + 16 + c];
      }
    }
    float4v z = {0.f, 0.f, 0.f, 0.f};
    float4v a0 = __builtin_amdgcn_mfma_f32_16x16x32_bf16(afA, bfr0, z, 0, 0, 0);
    float4v a1 = __builtin_amdgcn_mfma_f32_16x16x32_bf16(afA, bfr1, z, 0, 0, 0);
    #pragma unroll
    for (int p = 0; p < 4; p++){
      int el2 = tl*16 + q*4 + p;
      if (el2 < NEPS){
        sum0 += silu_f(a0[p] + preB0 + sbA0[p]);
        sum1 += silu_f(a1[p] + preB1 + sbA1[p]);
      }
    }
    if (s < 11){
      afA = afB;
      #pragma unroll
      for (int p = 0; p < 4; p++){ sbA0[p] = sbB0[p]; sbA1[p] = sbB1[p]; }
    }
  }
  sum0 += __shfl_xor(sum0, 16); sum0 += __shfl_xor(sum0, 32);
  sum1 += __shfl_xor(sum1, 16); sum1 += __shfl_xor(sum1, 32);
  if (lane < 16){ wsum[w][lane] = sum0; wsum[w][16 + lane] = sum1; }
  __syncthreads();
  if (t < 32) hsumL[t] = wsum[0][t] + wsum[1][t] + wsum[2][t] + wsum[3][t];
  __syncthreads();
  if (t < 32){
    float y = 0.f;
    #pragma unroll
    for (int m = 0; m < 32; m++) y = fmaf(hsumL[m], w1L[m*32 + t], y);
    msgL[t] = y * (1.f/767.f) + g_c[C_MP2B1 + t];
  }

  if (t < 64) catU[t] = g_ws[OFF_EMB1 + i*64 + t];
  if (t < 32){ catU[64 + t] = msgL[t]; aggL[t] = g_ws[OFF_EMB0 + i*32 + t]; }
  for (int idx = t; idx < 522; idx += 256) noL[idx] = g_c[C_NOW0 + idx];
  __syncthreads();

  // update MLP 2: layer A (96x64)
  int g = t >> 6, col = t & 63;
  {
    const float* w0 = g_c + C_UP2W0;
    float p0 = 0.f;
    #pragma unroll
    for (int j = 0; j < 24; j++){ int k = g*24 + j; p0 = fmaf(catU[k], w0[k*64 + col], p0); }
    part[t] = p0;
  }
  __syncthreads();
  if (t < 64) hU[t] = silu_f(g_c[C_UP2B0 + t] + part[t] + part[64+t] + part[128+t] + part[192+t]);
  __syncthreads();
  {
    const float* w1u = g_c + C_UP2W1;
    float p1 = 0.f;
    #pragma unroll
    for (int j = 0; j < 16; j++){ int k = g*16 + j; p1 = fmaf(hU[k], w1u[k*64 + col], p1); }
    part[t] = p1;
  }
  __syncthreads();
  if (t < 64){
    float y = g_c[C_UP2B1 + t] + part[t] + part[64+t] + part[128+t] + part[192+t];
    float e2 = catU[t] + y;
    aggL[32 + t] = catU[t];
    aggL[96 + t] = e2;
  }
  __syncthreads();
  if (t < 48){
    int chunk = t / 3, c3 = t - chunk*3;
    float p = 0.f;
    #pragma unroll
    for (int j = 0; j < 10; j++){ int k = chunk*10 + j; p = fmaf(aggL[k], noL[k*3 + c3], p); }
    part[t] = p;
  }
  __syncthreads();
  if (t < 3){
    float p = noL[480 + t];
    #pragma unroll
    for (int ch = 0; ch < 16; ch++) p += part[ch*3 + t];
    h3L[t] = silu_f(p);
  }
  __syncthreads();
  if (t < 3){
    float o = 0.f;
    #pragma unroll
    for (int m = 0; m < 3; m++) o = fmaf(h3L[m], noL[483 + m*3 + t], o);
    o += noL[492 + charges[i]*3 + t];
    if (g_isf) ((float*)out)[i*3 + t] = o;
    else       ((bf16*)out)[i*3 + t] = __float2bfloat16(o);
  }
  // global aggregation (no fence: __syncthreads drains vmcnt -> atomics performed)
  if (t < 160) atomicAdd(&g_agg[(i & 3)*160 + t], aggL[t]);
  __syncthreads();
  if (t == 0) lastL = (atomicAdd(&g_cnt, 1) == NN - 1) ? 1 : 0;
  __syncthreads();
  if (lastL){
    float v = 0.f;
    if (t < 160){
      float s = atomicAdd(&g_agg[t], 0.f) + atomicAdd(&g_agg[160 + t], 0.f)
              + atomicAdd(&g_agg[320 + t], 0.f) + atomicAdd(&g_agg[480 + t], 0.f);
      v = s * (1.f/768.f) * g_c[C_GOW0 + t];
    }
    part[t] = v;
    __syncthreads();
    if (t == 0){
      float tot = 0.f;
      for (int k = 0; k < 160; k++) tot += part[k];
      float h = silu_f(tot + g_c[C_GOB0]);
      float go = h * g_c[C_GOW1] + g_c[C_GOB1];
      if (g_isf) ((float*)out)[2304] = go;
      else       ((bf16*)out)[2304] = __float2bfloat16(go);
    }
  }
}

extern "C" void kernel_launch(void* const* d_in, const int* in_sizes, int n_in,
                              void* d_out, int out_size, void* d_ws, size_t ws_size,
                              hipStream_t stream) {
  Ptrs P;
  for (int k = 0; k < 28; k++) P.p[k] = d_in[k];
  const int* charges = (const int*)d_in[1];

  k_conv_prep<<<96, 256, 0, stream>>>(P, charges);
  k_edge1<<<NN, 256, 0, stream>>>();
  k_edge2<<<NN, 256, 0, stream>>>(charges, d_out);
}